// Round 2
// baseline (324.498 us; speedup 1.0000x reference)
//
#include <hip/hip_runtime.h>
#include <hip/hip_bf16.h>

#define B_    32
#define N_    196
#define H_    14
#define DIMC  384
#define NQKV  896
#define DQK   256
#define DV    384
#define NH    12
#define CG    32
#define NPW   588
#define PAD_  3
#define SCALE_ 0.17677669529663687f   // (384/12)^-0.5

// ---------------------------------------------------------------------------
// K1: qkv = x @ w_qkv^T + b_qkv ; scatter to channel-major qT/kT/vT [B][C][196]
// M = 6272 (=98*64), Nout = 896 (=14*64), K = 384
// ---------------------------------------------------------------------------
__global__ __launch_bounds__(256) void k_qkv(const float* __restrict__ x,
    const float* __restrict__ w, const float* __restrict__ bias,
    float* __restrict__ qT, float* __restrict__ kT, float* __restrict__ vT)
{
    __shared__ float As[16][64];
    __shared__ float Bs[16][64];
    const int t  = threadIdx.x;
    const int m0 = blockIdx.x * 64;
    const int o0 = blockIdx.y * 64;
    const int lr = t >> 2;            // 0..63
    const int lk = (t & 3) << 2;      // 0,4,8,12
    const int tr = (t >> 4) << 2;     // row offset 0..60
    const int tc = (t & 15) << 2;     // col offset 0..60
    float acc[4][4] = {};
    for (int k0 = 0; k0 < DIMC; k0 += 16) {
        float4 av = *(const float4*)(x + (size_t)(m0 + lr) * DIMC + k0 + lk);
        float4 bv = *(const float4*)(w + (size_t)(o0 + lr) * DIMC + k0 + lk);
        As[lk+0][lr] = av.x; As[lk+1][lr] = av.y; As[lk+2][lr] = av.z; As[lk+3][lr] = av.w;
        Bs[lk+0][lr] = bv.x; Bs[lk+1][lr] = bv.y; Bs[lk+2][lr] = bv.z; Bs[lk+3][lr] = bv.w;
        __syncthreads();
        #pragma unroll
        for (int kk = 0; kk < 16; ++kk) {
            const float4 a = *(const float4*)&As[kk][tr];
            const float4 b = *(const float4*)&Bs[kk][tc];
            const float avr[4] = {a.x, a.y, a.z, a.w};
            const float bvr[4] = {b.x, b.y, b.z, b.w};
            #pragma unroll
            for (int i = 0; i < 4; ++i)
                #pragma unroll
                for (int j = 0; j < 4; ++j)
                    acc[i][j] += avr[i] * bvr[j];
        }
        __syncthreads();
    }
    #pragma unroll
    for (int i = 0; i < 4; ++i) {
        const int m  = m0 + tr + i;
        const int bb = m / N_;
        const int n  = m - bb * N_;
        #pragma unroll
        for (int j = 0; j < 4; ++j) {
            const int o = o0 + tc + j;
            const float val = acc[i][j] + bias[o];
            if (o < DQK)          qT[((size_t)bb * DQK + o) * N_ + n] = val;
            else if (o < 2*DQK)   kT[((size_t)bb * DQK + (o - DQK)) * N_ + n] = val;
            else                  vT[((size_t)bb * DV  + (o - 2*DQK)) * N_ + n] = val;
        }
    }
}

// ---------------------------------------------------------------------------
// K2: hp = q*k*SCALE ; grouped 7x7 conv (32 groups, width 8) ; +bias ; GELU
// block = (batch, group-pair): 2 groups => 16 in-ch, 16 out-ch
// ---------------------------------------------------------------------------
__global__ __launch_bounds__(256) void k_dwconv(const float* __restrict__ qT,
    const float* __restrict__ kT, const float* __restrict__ w_dw,
    const float* __restrict__ b_dw, float* __restrict__ h1)
{
    const int b  = blockIdx.x;   // 32
    const int gp = blockIdx.y;   // 16 group-pairs
    __shared__ float hp[16 * 400];    // 16 ch x 20x20 padded
    __shared__ float wsm[16 * 392];   // 16 oc x (8 ic * 49)
    const int t = threadIdx.x;
    for (int i = t; i < 16 * 400; i += 256) hp[i] = 0.f;
    for (int i = t; i < 16 * 392; i += 256) wsm[i] = w_dw[gp * 6272 + i];
    __syncthreads();
    for (int i = t; i < 16 * N_; i += 256) {
        const int cl = i / N_;
        const int n  = i - cl * N_;
        const int y  = n / H_, x = n - y * H_;
        const size_t gi = ((size_t)b * DQK + gp * 16 + cl) * N_ + n;
        hp[cl * 400 + (y + PAD_) * 20 + (x + PAD_)] = qT[gi] * kT[gi] * SCALE_;
    }
    __syncthreads();
    if (t < 224) {
        const int od = t / 14;          // 0..15
        const int y  = t - od * 14;     // 0..13
        const int icb = (od >> 3) << 3; // 0 or 8 (group select)
        float acc[14];
        #pragma unroll
        for (int x = 0; x < 14; ++x) acc[x] = 0.f;
        for (int ic = 0; ic < 8; ++ic) {
            const float* hrow = &hp[(icb + ic) * 400];
            const float* wrow = &wsm[od * 392 + ic * 49];
            #pragma unroll
            for (int ky = 0; ky < 7; ++ky) {
                float r[20];
                #pragma unroll
                for (int ii = 0; ii < 20; ii += 4)
                    *(float4*)&r[ii] = *(const float4*)&hrow[(y + ky) * 20 + ii];
                #pragma unroll
                for (int kx = 0; kx < 7; ++kx) {
                    const float wv = wrow[ky * 7 + kx];
                    #pragma unroll
                    for (int x = 0; x < 14; ++x)
                        acc[x] += r[x + kx] * wv;
                }
            }
        }
        const float bv = b_dw[gp * 16 + od];
        #pragma unroll
        for (int x = 0; x < 14; ++x) {
            const float s = acc[x] + bv;
            const float gv = 0.5f * s * (1.f + erff(s * 0.70710678118654752440f));
            h1[((size_t)b * DQK + gp * 16 + od) * N_ + y * H_ + x] = gv;
        }
    }
}

// ---------------------------------------------------------------------------
// K3: h2[b][oc][n] = sum_c w_pw[oc][c] * h1[b][c][n] + b_pw[oc]
// per-batch GEMM: M=588, N=196, K=256
// ---------------------------------------------------------------------------
__global__ __launch_bounds__(256) void k_pw(const float* __restrict__ w_pw,
    const float* __restrict__ b_pw, const float* __restrict__ h1,
    float* __restrict__ h2)
{
    const int b  = blockIdx.z;
    const int n0 = blockIdx.x * 64;   // 0..3
    const int o0 = blockIdx.y * 64;   // 0..9
    __shared__ float As[16][64];      // w_pw tile, As[kk][oc_l]
    __shared__ float Bs[16][64];      // h1 tile,   Bs[kk][n_l]
    const int t   = threadIdx.x;
    const int lr  = t >> 2;           // A row 0..63
    const int lk  = (t & 3) << 2;     // A k 0,4,8,12
    const int bkk = t >> 4;           // B k row 0..15
    const int bn4 = (t & 15) << 2;    // B n col 0..60
    const int tr  = (t >> 4) << 2;
    const int tc  = (t & 15) << 2;
    float acc[4][4] = {};
    for (int k0 = 0; k0 < DQK; k0 += 16) {
        float4 av = make_float4(0.f, 0.f, 0.f, 0.f);
        if (o0 + lr < NPW)
            av = *(const float4*)(w_pw + (size_t)(o0 + lr) * DQK + k0 + lk);
        float4 bv = make_float4(0.f, 0.f, 0.f, 0.f);
        if (n0 + bn4 < N_)
            bv = *(const float4*)(h1 + ((size_t)b * DQK + k0 + bkk) * N_ + n0 + bn4);
        As[lk+0][lr] = av.x; As[lk+1][lr] = av.y; As[lk+2][lr] = av.z; As[lk+3][lr] = av.w;
        *(float4*)&Bs[bkk][bn4] = bv;
        __syncthreads();
        #pragma unroll
        for (int kk = 0; kk < 16; ++kk) {
            const float4 a = *(const float4*)&As[kk][tr];
            const float4 bq = *(const float4*)&Bs[kk][tc];
            const float avr[4] = {a.x, a.y, a.z, a.w};
            const float bvr[4] = {bq.x, bq.y, bq.z, bq.w};
            #pragma unroll
            for (int i = 0; i < 4; ++i)
                #pragma unroll
                for (int j = 0; j < 4; ++j)
                    acc[i][j] += avr[i] * bvr[j];
        }
        __syncthreads();
    }
    if (n0 + tc < N_) {
        #pragma unroll
        for (int i = 0; i < 4; ++i) {
            const int oc = o0 + tr + i;
            if (oc < NPW) {
                const float bb = b_pw[oc];
                float4 out;
                out.x = acc[i][0] + bb; out.y = acc[i][1] + bb;
                out.z = acc[i][2] + bb; out.w = acc[i][3] + bb;
                *(float4*)(h2 + ((size_t)b * NPW + oc) * N_ + n0 + tc) = out;
            }
        }
    }
}

// ---------------------------------------------------------------------------
// K4: softmax over 49 kernel positions + ELSA windowed sum
// block = (batch, head); out_rm[b][n][C] row-major for final GEMM
// Static LDS, channel-chunked (8 ch / chunk) to stay under the 64 KB
// per-block dynamic/static LDS launch limit: 9604+3208+784 = 13596 f = 54.4 KB
// ---------------------------------------------------------------------------
__global__ __launch_bounds__(256) void k_elsa(const float* __restrict__ h2,
    const float* __restrict__ vT, const float* __restrict__ ghost,
    float* __restrict__ out_rm)
{
    const int b = blockIdx.x;   // 32
    const int g = blockIdx.y;   // 12
    __shared__ float attn[49 * N_];       // 9604 floats
    __shared__ float vp[8 * 401];         // 3208 floats (odd stride: bank-spread)
    __shared__ float gm[8 * 49];          // 392
    __shared__ float ga[8 * 49];          // 392
    const int t = threadIdx.x;

    // load attention logits
    const float* src = h2 + ((size_t)b * NPW + g * 49) * N_;
    for (int i = t; i < 49 * N_; i += 256) attn[i] = src[i];
    __syncthreads();

    // softmax over p for column n = t
    if (t < N_) {
        float mx = -1e30f;
        for (int p = 0; p < 49; ++p) mx = fmaxf(mx, attn[p * N_ + t]);
        float s = 0.f;
        for (int p = 0; p < 49; ++p) {
            const float e = expf(attn[p * N_ + t] - mx);
            attn[p * N_ + t] = e;
            s += e;
        }
        const float inv = 1.f / s;
        for (int p = 0; p < 49; ++p) attn[p * N_ + t] *= inv;
    }
    __syncthreads();

    // 4 chunks of 8 channels
    for (int cc = 0; cc < 4; ++cc) {
        const int c0 = cc * 8;            // channel base within head
        // zero pad region + fill interior + ghost coefs
        for (int i = t; i < 8 * 401; i += 256) vp[i] = 0.f;
        for (int i = t; i < 8 * 49; i += 256) {
            gm[i] = ghost[(size_t)(g * CG + c0) * 49 + i];            // ghost_mul ^ 1
            ga[i] = ghost[(size_t)DV * 49 + (g * CG + c0) * 49 + i];  // ghost_add * 1
        }
        __syncthreads();
        for (int i = t; i < 8 * N_; i += 256) {
            const int c = i / N_;
            const int n = i - c * N_;
            const int y = n / H_, x = n - y * H_;
            vp[c * 401 + (y + PAD_) * 20 + (x + PAD_)] =
                vT[((size_t)b * DV + g * CG + c0 + c) * N_ + n];
        }
        __syncthreads();

        for (int idx = t; idx < 8 * N_; idx += 256) {
            const int c = idx & 7;         // channel within chunk
            const int n = idx >> 3;        // spatial
            const int y = n / H_, x = n - y * H_;
            const float* vrow = &vp[c * 401];
            const float* gmr  = &gm[c * 49];
            const float* gar  = &ga[c * 49];
            float s = 0.f;
            #pragma unroll
            for (int ky = 0; ky < 7; ++ky)
                #pragma unroll
                for (int kx = 0; kx < 7; ++kx) {
                    const int p = ky * 7 + kx;
                    s += vrow[(y + ky) * 20 + (x + kx)]
                       * (gmr[p] * attn[p * N_ + n] + gar[p]);
                }
            out_rm[((size_t)b * N_ + n) * DV + g * CG + c0 + c] = s;
        }
        __syncthreads();
    }
}

// ---------------------------------------------------------------------------
// K5: y = out_rm @ w_proj^T + b_proj ; M=6272, Nout=384, K=384
// ---------------------------------------------------------------------------
__global__ __launch_bounds__(256) void k_proj(const float* __restrict__ A,
    const float* __restrict__ w, const float* __restrict__ bias,
    float* __restrict__ y)
{
    __shared__ float As[16][64];
    __shared__ float Bs[16][64];
    const int t  = threadIdx.x;
    const int m0 = blockIdx.x * 64;
    const int o0 = blockIdx.y * 64;
    const int lr = t >> 2;
    const int lk = (t & 3) << 2;
    const int tr = (t >> 4) << 2;
    const int tc = (t & 15) << 2;
    float acc[4][4] = {};
    for (int k0 = 0; k0 < DV; k0 += 16) {
        float4 av = *(const float4*)(A + (size_t)(m0 + lr) * DV + k0 + lk);
        float4 bv = *(const float4*)(w + (size_t)(o0 + lr) * DV + k0 + lk);
        As[lk+0][lr] = av.x; As[lk+1][lr] = av.y; As[lk+2][lr] = av.z; As[lk+3][lr] = av.w;
        Bs[lk+0][lr] = bv.x; Bs[lk+1][lr] = bv.y; Bs[lk+2][lr] = bv.z; Bs[lk+3][lr] = bv.w;
        __syncthreads();
        #pragma unroll
        for (int kk = 0; kk < 16; ++kk) {
            const float4 a = *(const float4*)&As[kk][tr];
            const float4 bq = *(const float4*)&Bs[kk][tc];
            const float avr[4] = {a.x, a.y, a.z, a.w};
            const float bvr[4] = {bq.x, bq.y, bq.z, bq.w};
            #pragma unroll
            for (int i = 0; i < 4; ++i)
                #pragma unroll
                for (int j = 0; j < 4; ++j)
                    acc[i][j] += avr[i] * bvr[j];
        }
        __syncthreads();
    }
    const float4 bb = *(const float4*)&bias[o0 + tc];
    #pragma unroll
    for (int i = 0; i < 4; ++i) {
        float4 out;
        out.x = acc[i][0] + bb.x; out.y = acc[i][1] + bb.y;
        out.z = acc[i][2] + bb.z; out.w = acc[i][3] + bb.w;
        *(float4*)(y + (size_t)(m0 + tr + i) * DV + o0 + tc) = out;
    }
}

// ---------------------------------------------------------------------------
extern "C" void kernel_launch(void* const* d_in, const int* in_sizes, int n_in,
                              void* d_out, int out_size, void* d_ws, size_t ws_size,
                              hipStream_t stream)
{
    const float* x      = (const float*)d_in[0];
    const float* w_qkv  = (const float*)d_in[1];
    const float* b_qkv  = (const float*)d_in[2];
    const float* w_dw   = (const float*)d_in[3];
    const float* b_dw   = (const float*)d_in[4];
    const float* w_pw   = (const float*)d_in[5];
    const float* b_pw   = (const float*)d_in[6];
    const float* ghost  = (const float*)d_in[7];
    const float* w_proj = (const float*)d_in[8];
    const float* b_proj = (const float*)d_in[9];
    float* y  = (float*)d_out;
    float* ws = (float*)d_ws;

    float* qT  = ws;                                  // [32][256][196]
    float* kT  = qT  + (size_t)B_ * DQK * N_;         // [32][256][196]
    float* vT  = kT  + (size_t)B_ * DQK * N_;         // [32][384][196]
    float* h1  = vT  + (size_t)B_ * DV  * N_;         // [32][256][196]
    float* h2  = h1  + (size_t)B_ * DQK * N_;         // [32][588][196]
    float* orm = h2  + (size_t)B_ * NPW * N_;         // [32][196][384]

    k_qkv   <<<dim3(98, 14),    256, 0, stream>>>(x, w_qkv, b_qkv, qT, kT, vT);
    k_dwconv<<<dim3(32, 16),    256, 0, stream>>>(qT, kT, w_dw, b_dw, h1);
    k_pw    <<<dim3(4, 10, 32), 256, 0, stream>>>(w_pw, b_pw, h1, h2);
    k_elsa  <<<dim3(32, 12),    256, 0, stream>>>(h2, vT, ghost, orm);
    k_proj  <<<dim3(98, 6),     256, 0, stream>>>(orm, w_proj, b_proj, y);
}

// Round 7
// 260.009 us; speedup vs baseline: 1.2480x; 1.2480x over previous
//
#include <hip/hip_runtime.h>
#include <hip/hip_bf16.h>

#define B_    32
#define N_    196
#define H_    14
#define DIMC  384
#define DQK   256
#define DV    384
#define NH    12
#define CG    32
#define NPW   588
#define PAD_  3
#define SCALE_ 0.17677669529663687f   // (384/12)^-0.5

typedef __bf16 bf16x8 __attribute__((ext_vector_type(8)));
typedef float  f32x4  __attribute__((ext_vector_type(4)));

__device__ inline bf16x8 bf16x8_zero() {
    bf16x8 z;
    #pragma unroll
    for (int j = 0; j < 8; ++j) z[j] = (__bf16)0.0f;
    return z;
}

__device__ inline void split2(float v, __hip_bfloat16& h, __hip_bfloat16& l) {
    h = __float2bfloat16(v);
    l = __float2bfloat16(v - __bfloat162float(h));
}

// ---------------------------------------------------------------------------
// K0: split fp32 -> (hi,lo) bf16 for x, w_qkv, w_pw, w_proj. float4 per thread.
// segment float4 boundaries: x 602112 | wqkv 86016 | wpw 37632 | wproj 36864
// ---------------------------------------------------------------------------
__global__ __launch_bounds__(256) void k_split(
    const float* __restrict__ s0, const float* __restrict__ s1,
    const float* __restrict__ s2, const float* __restrict__ s3,
    __hip_bfloat16* __restrict__ h0, __hip_bfloat16* __restrict__ l0,
    __hip_bfloat16* __restrict__ h1, __hip_bfloat16* __restrict__ l1,
    __hip_bfloat16* __restrict__ h2, __hip_bfloat16* __restrict__ l2,
    __hip_bfloat16* __restrict__ h3, __hip_bfloat16* __restrict__ l3)
{
    int i = blockIdx.x * 256 + threadIdx.x;
    if (i >= 762624) return;
    const float* src; __hip_bfloat16 *dh, *dl; int off;
    if      (i < 602112) { src = s0; dh = h0; dl = l0; off = i; }
    else if (i < 688128) { src = s1; dh = h1; dl = l1; off = i - 602112; }
    else if (i < 725760) { src = s2; dh = h2; dl = l2; off = i - 688128; }
    else                 { src = s3; dh = h3; dl = l3; off = i - 725760; }
    const float4 v = ((const float4*)src)[off];
    union { __hip_bfloat16 b[4]; uint2 u; } H, L;
    split2(v.x, H.b[0], L.b[0]); split2(v.y, H.b[1], L.b[1]);
    split2(v.z, H.b[2], L.b[2]); split2(v.w, H.b[3], L.b[3]);
    ((uint2*)dh)[off] = H.u;
    ((uint2*)dl)[off] = L.u;
}

// ---------------------------------------------------------------------------
// Split-bf16 MFMA GEMM: C[M x N] = P[M x K] @ Q[N x K]^T (+bias), 3-pass hi/lo.
// 128x128 tile, 4 waves each 64x64 (4x4 frags of 16x16x32), BK=32.
// LDS XOR swizzle: byte ^= (row&7)<<4 (row stride 64B); bijective, same map on
// read side. EPI 0: qkv scatter to channel-major qT/kT/vT. EPI 1: h2t
// (guard col<588). EPI 2: y row-major.
// ---------------------------------------------------------------------------
template<int EPI>
__global__ __launch_bounds__(256) void k_mfma(
    const __hip_bfloat16* __restrict__ Phi, const __hip_bfloat16* __restrict__ Plo,
    const __hip_bfloat16* __restrict__ Qhi, const __hip_bfloat16* __restrict__ Qlo,
    const float* __restrict__ bias, int K, int nQ,
    float* __restrict__ out0, float* __restrict__ out1, float* __restrict__ out2)
{
    __shared__ ushort lds[16384];   // Ahi[0:4096) Alo[4096) Bhi[8192) Blo[12288) (ushort idx)
    const int t    = threadIdx.x;
    const int m0   = blockIdx.x * 128;
    const int n0   = blockIdx.y * 128;
    const int lane = t & 63;
    const int wv   = t >> 6;
    const int wm   = (wv >> 1) * 64;
    const int wn   = (wv & 1) * 64;
    const int l16  = lane & 15;
    const int kb   = lane >> 4;          // 0..3

    f32x4 acc[4][4];
    #pragma unroll
    for (int mi = 0; mi < 4; ++mi)
        #pragma unroll
        for (int nj = 0; nj < 4; ++nj) acc[mi][nj] = f32x4{0.f, 0.f, 0.f, 0.f};

    for (int k0 = 0; k0 < K; k0 += 32) {
        bf16x8 rA[2][2], rB[2][2];
        #pragma unroll
        for (int q = 0; q < 2; ++q) {
            const int u = q * 256 + t;
            const int r = u >> 2;
            const int kk = (u & 3) * 8;
            const size_t pOff = (size_t)(m0 + r) * K + k0 + kk;
            rA[q][0] = *(const bf16x8*)(Phi + pOff);
            rA[q][1] = *(const bf16x8*)(Plo + pOff);
            if (n0 + r < nQ) {
                const size_t qOff = (size_t)(n0 + r) * K + k0 + kk;
                rB[q][0] = *(const bf16x8*)(Qhi + qOff);
                rB[q][1] = *(const bf16x8*)(Qlo + qOff);
            } else { rB[q][0] = bf16x8_zero(); rB[q][1] = bf16x8_zero(); }
        }
        __syncthreads();   // prior iteration's LDS reads complete
        #pragma unroll
        for (int q = 0; q < 2; ++q) {
            const int u  = q * 256 + t;
            const int r  = u >> 2;
            const int sw = ((u << 4) ^ ((r & 7) << 4)) >> 1;   // ushort index
            *(bf16x8*)&lds[sw]         = rA[q][0];
            *(bf16x8*)&lds[sw + 4096]  = rA[q][1];
            *(bf16x8*)&lds[sw + 8192]  = rB[q][0];
            *(bf16x8*)&lds[sw + 12288] = rB[q][1];
        }
        __syncthreads();
        bf16x8 bh[4], bl[4];
        #pragma unroll
        for (int nj = 0; nj < 4; ++nj) {
            const int br  = wn + nj * 16 + l16;
            const int idx = ((br * 64 + kb * 16) ^ ((br & 7) << 4)) >> 1;
            bh[nj] = *(const bf16x8*)&lds[8192 + idx];
            bl[nj] = *(const bf16x8*)&lds[12288 + idx];
        }
        #pragma unroll
        for (int mi = 0; mi < 4; ++mi) {
            const int ar  = wm + mi * 16 + l16;
            const int idx = ((ar * 64 + kb * 16) ^ ((ar & 7) << 4)) >> 1;
            const bf16x8 ah = *(const bf16x8*)&lds[idx];
            const bf16x8 al = *(const bf16x8*)&lds[4096 + idx];
            #pragma unroll
            for (int nj = 0; nj < 4; ++nj) {
                acc[mi][nj] = __builtin_amdgcn_mfma_f32_16x16x32_bf16(ah, bh[nj], acc[mi][nj], 0, 0, 0);
                acc[mi][nj] = __builtin_amdgcn_mfma_f32_16x16x32_bf16(ah, bl[nj], acc[mi][nj], 0, 0, 0);
                acc[mi][nj] = __builtin_amdgcn_mfma_f32_16x16x32_bf16(al, bh[nj], acc[mi][nj], 0, 0, 0);
            }
        }
    }

    #pragma unroll
    for (int mi = 0; mi < 4; ++mi) {
        #pragma unroll
        for (int r = 0; r < 4; ++r) {
            const int m = m0 + wm + mi * 16 + kb * 4 + r;   // row = (lane>>4)*4 + reg
            #pragma unroll
            for (int nj = 0; nj < 4; ++nj) {
                const int col = n0 + wn + nj * 16 + l16;    // col = lane&15
                const float v = acc[mi][nj][r];
                if (EPI == 0) {
                    const float val = v + bias[col];
                    const int bb = m / N_, n = m - bb * N_;
                    if (col < DQK)          out0[((size_t)bb * DQK + col) * N_ + n] = val;
                    else if (col < 2*DQK)   out1[((size_t)bb * DQK + (col - DQK)) * N_ + n] = val;
                    else                    out2[((size_t)bb * DV + (col - 2*DQK)) * N_ + n] = val;
                } else if (EPI == 1) {
                    if (col < NPW) out0[(size_t)m * NPW + col] = v + bias[col];
                } else {
                    out0[(size_t)m * DV + col] = v + bias[col];
                }
            }
        }
    }
}

// ---------------------------------------------------------------------------
// K2: hp = q*k*SCALE ; grouped 7x7 conv ; +bias ; GELU -> split-bf16 h1t[b*n][256]
// ---------------------------------------------------------------------------
__global__ __launch_bounds__(256) void k_dwconv(const float* __restrict__ qT,
    const float* __restrict__ kT, const float* __restrict__ w_dw,
    const float* __restrict__ b_dw,
    __hip_bfloat16* __restrict__ h1t_hi, __hip_bfloat16* __restrict__ h1t_lo)
{
    const int b  = blockIdx.x;   // 32
    const int gp = blockIdx.y;   // 16 group-pairs
    __shared__ float hp[16 * 400];
    __shared__ float wsm[16 * 392];
    const int t = threadIdx.x;
    for (int i = t; i < 16 * 400; i += 256) hp[i] = 0.f;
    for (int i = t; i < 16 * 392; i += 256) wsm[i] = w_dw[gp * 6272 + i];
    __syncthreads();
    for (int i = t; i < 16 * N_; i += 256) {
        const int cl = i / N_;
        const int n  = i - cl * N_;
        const int y  = n / H_, x = n - y * H_;
        const size_t gi = ((size_t)b * DQK + gp * 16 + cl) * N_ + n;
        hp[cl * 400 + (y + PAD_) * 20 + (x + PAD_)] = qT[gi] * kT[gi] * SCALE_;
    }
    __syncthreads();
    if (t < 224) {
        const int od = t / 14;
        const int y  = t - od * 14;
        const int icb = (od >> 3) << 3;
        float acc[14];
        #pragma unroll
        for (int x = 0; x < 14; ++x) acc[x] = 0.f;
        for (int ic = 0; ic < 8; ++ic) {
            const float* hrow = &hp[(icb + ic) * 400];
            const float* wrow = &wsm[od * 392 + ic * 49];
            #pragma unroll
            for (int ky = 0; ky < 7; ++ky) {
                float r[20];
                #pragma unroll
                for (int ii = 0; ii < 20; ii += 4)
                    *(float4*)&r[ii] = *(const float4*)&hrow[(y + ky) * 20 + ii];
                #pragma unroll
                for (int kx = 0; kx < 7; ++kx) {
                    const float wv = wrow[ky * 7 + kx];
                    #pragma unroll
                    for (int x = 0; x < 14; ++x)
                        acc[x] += r[x + kx] * wv;
                }
            }
        }
        const float bv = b_dw[gp * 16 + od];
        const int c = gp * 16 + od;
        #pragma unroll
        for (int x = 0; x < 14; ++x) {
            const float s  = acc[x] + bv;
            const float gv = 0.5f * s * (1.f + erff(s * 0.70710678118654752440f));
            __hip_bfloat16 hb, lb; split2(gv, hb, lb);
            const size_t o = ((size_t)b * N_ + y * H_ + x) * DQK + c;
            h1t_hi[o] = hb; h1t_lo[o] = lb;
        }
    }
}

// ---------------------------------------------------------------------------
// K4: softmax over 49 positions + ELSA windowed sum; h2t[b*n][588] input;
// split-bf16 orm[b*n][384] output.
// ---------------------------------------------------------------------------
__global__ __launch_bounds__(256) void k_elsa(const float* __restrict__ h2t,
    const float* __restrict__ vT, const float* __restrict__ ghost,
    __hip_bfloat16* __restrict__ orm_hi, __hip_bfloat16* __restrict__ orm_lo)
{
    const int b = blockIdx.x;   // 32
    const int g = blockIdx.y;   // 12
    __shared__ float attn[49 * N_];       // 9604 floats
    __shared__ float vp[8 * 401];
    __shared__ float gm[8 * 49];
    __shared__ float ga[8 * 49];
    const int t = threadIdx.x;

    const float* src = h2t + (size_t)b * N_ * NPW + g * 49;
    for (int i = t; i < 49 * N_; i += 256) {
        const int n = i / 49, p = i - n * 49;
        attn[p * N_ + n] = src[(size_t)n * NPW + p];
    }
    __syncthreads();

    if (t < N_) {
        float mx = -1e30f;
        for (int p = 0; p < 49; ++p) mx = fmaxf(mx, attn[p * N_ + t]);
        float s = 0.f;
        for (int p = 0; p < 49; ++p) {
            const float e = expf(attn[p * N_ + t] - mx);
            attn[p * N_ + t] = e;
            s += e;
        }
        const float inv = 1.f / s;
        for (int p = 0; p < 49; ++p) attn[p * N_ + t] *= inv;
    }
    __syncthreads();

    for (int cc = 0; cc < 4; ++cc) {
        const int c0 = cc * 8;
        for (int i = t; i < 8 * 401; i += 256) vp[i] = 0.f;
        for (int i = t; i < 8 * 49; i += 256) {
            gm[i] = ghost[(size_t)(g * CG + c0) * 49 + i];
            ga[i] = ghost[(size_t)DV * 49 + (g * CG + c0) * 49 + i];
        }
        __syncthreads();
        for (int i = t; i < 8 * N_; i += 256) {
            const int c = i / N_;
            const int n = i - c * N_;
            const int y = n / H_, x = n - y * H_;
            vp[c * 401 + (y + PAD_) * 20 + (x + PAD_)] =
                vT[((size_t)b * DV + g * CG + c0 + c) * N_ + n];
        }
        __syncthreads();

        for (int idx = t; idx < 8 * N_; idx += 256) {
            const int c = idx & 7;
            const int n = idx >> 3;
            const int y = n / H_, x = n - y * H_;
            const float* vrow = &vp[c * 401];
            const float* gmr  = &gm[c * 49];
            const float* gar  = &ga[c * 49];
            float s = 0.f;
            #pragma unroll
            for (int ky = 0; ky < 7; ++ky)
                #pragma unroll
                for (int kx = 0; kx < 7; ++kx) {
                    const int p = ky * 7 + kx;
                    s += vrow[(y + ky) * 20 + (x + kx)]
                       * (gmr[p] * attn[p * N_ + n] + gar[p]);
                }
            __hip_bfloat16 hb, lb; split2(s, hb, lb);
            const size_t o = ((size_t)b * N_ + n) * DV + g * CG + c0 + c;
            orm_hi[o] = hb; orm_lo[o] = lb;
        }
        __syncthreads();
    }
}

// ---------------------------------------------------------------------------
extern "C" void kernel_launch(void* const* d_in, const int* in_sizes, int n_in,
                              void* d_out, int out_size, void* d_ws, size_t ws_size,
                              hipStream_t stream)
{
    const float* x      = (const float*)d_in[0];
    const float* w_qkv  = (const float*)d_in[1];
    const float* b_qkv  = (const float*)d_in[2];
    const float* w_dw   = (const float*)d_in[3];
    const float* b_dw   = (const float*)d_in[4];
    const float* w_pw   = (const float*)d_in[5];
    const float* b_pw   = (const float*)d_in[6];
    const float* ghost  = (const float*)d_in[7];
    const float* w_proj = (const float*)d_in[8];
    const float* b_proj = (const float*)d_in[9];
    float* y  = (float*)d_out;
    char* ws = (char*)d_ws;

    // Aliasing plan (stream-ordered lifetimes), peak 44.8 MB:
    //   [0,14751744):      x_hi/x_lo/wqkv_hi/wqkv_lo (live through qkv)
    //                      then h2t (written by pw, read by elsa)
    //   [14751744,27596800): qT,kT (live through dwconv)
    //                      then orm_hi/orm_lo (written by elsa, read by proj)
    //   [27596800,37230592): vT (live through elsa)
    //   [37230592,44845056): wpw/wproj splits + h1t splits
    __hip_bfloat16* x_hi     = (__hip_bfloat16*)(ws + 0);
    __hip_bfloat16* x_lo     = (__hip_bfloat16*)(ws + 4816896);
    __hip_bfloat16* wqkv_hi  = (__hip_bfloat16*)(ws + 9633792);
    __hip_bfloat16* wqkv_lo  = (__hip_bfloat16*)(ws + 10321920);
    float*          h2t      = (float*)         (ws + 0);            // alias, 14751744 B
    float*          qT       = (float*)         (ws + 14751744);
    float*          kT       = (float*)         (ws + 21174272);
    __hip_bfloat16* orm_hi   = (__hip_bfloat16*)(ws + 14751744);     // alias qT/kT region
    __hip_bfloat16* orm_lo   = (__hip_bfloat16*)(ws + 19568640);
    float*          vT       = (float*)         (ws + 27596800);
    __hip_bfloat16* wpw_hi   = (__hip_bfloat16*)(ws + 37230592);
    __hip_bfloat16* wpw_lo   = (__hip_bfloat16*)(ws + 37531648);
    __hip_bfloat16* wproj_hi = (__hip_bfloat16*)(ws + 37832704);
    __hip_bfloat16* wproj_lo = (__hip_bfloat16*)(ws + 38127616);
    __hip_bfloat16* h1t_hi   = (__hip_bfloat16*)(ws + 38422528);
    __hip_bfloat16* h1t_lo   = (__hip_bfloat16*)(ws + 41633792);

    k_split<<<2979, 256, 0, stream>>>(x, w_qkv, w_pw, w_proj,
        x_hi, x_lo, wqkv_hi, wqkv_lo, wpw_hi, wpw_lo, wproj_hi, wproj_lo);

    k_mfma<0><<<dim3(49, 7), 256, 0, stream>>>(x_hi, x_lo, wqkv_hi, wqkv_lo,
        b_qkv, DIMC, 896, qT, kT, vT);

    k_dwconv<<<dim3(32, 16), 256, 0, stream>>>(qT, kT, w_dw, b_dw, h1t_hi, h1t_lo);

    k_mfma<1><<<dim3(49, 5), 256, 0, stream>>>(h1t_hi, h1t_lo, wpw_hi, wpw_lo,
        b_pw, DQK, NPW, h2t, nullptr, nullptr);

    k_elsa<<<dim3(32, 12), 256, 0, stream>>>(h2t, vT, ghost, orm_hi, orm_lo);

    k_mfma<2><<<dim3(49, 3), 256, 0, stream>>>(orm_hi, orm_lo, wproj_hi, wproj_lo,
        b_proj, DV, DV, y, nullptr, nullptr);
}

// Round 8
// 241.882 us; speedup vs baseline: 1.3416x; 1.0749x over previous
//
#include <hip/hip_runtime.h>
#include <hip/hip_bf16.h>

#define B_    32
#define N_    196
#define H_    14
#define DIMC  384
#define DQK   256
#define DV    384
#define NH    12
#define CG    32
#define NPW   588
#define PAD_  3
#define SCALE_ 0.17677669529663687f   // (384/12)^-0.5

typedef __bf16 bf16x8 __attribute__((ext_vector_type(8)));
typedef float  f32x4  __attribute__((ext_vector_type(4)));

__device__ inline bf16x8 bf16x8_zero() {
    bf16x8 z;
    #pragma unroll
    for (int j = 0; j < 8; ++j) z[j] = (__bf16)0.0f;
    return z;
}

__device__ inline void split2(float v, __hip_bfloat16& h, __hip_bfloat16& l) {
    h = __float2bfloat16(v);
    l = __float2bfloat16(v - __bfloat162float(h));
}

// ---------------------------------------------------------------------------
// K0: split fp32 -> (hi,lo) bf16 for x, w_qkv, w_pw, w_proj. float4 per thread.
// ---------------------------------------------------------------------------
__global__ __launch_bounds__(256) void k_split(
    const float* __restrict__ s0, const float* __restrict__ s1,
    const float* __restrict__ s2, const float* __restrict__ s3,
    __hip_bfloat16* __restrict__ h0, __hip_bfloat16* __restrict__ l0,
    __hip_bfloat16* __restrict__ h1, __hip_bfloat16* __restrict__ l1,
    __hip_bfloat16* __restrict__ h2, __hip_bfloat16* __restrict__ l2,
    __hip_bfloat16* __restrict__ h3, __hip_bfloat16* __restrict__ l3)
{
    int i = blockIdx.x * 256 + threadIdx.x;
    if (i >= 762624) return;
    const float* src; __hip_bfloat16 *dh, *dl; int off;
    if      (i < 602112) { src = s0; dh = h0; dl = l0; off = i; }
    else if (i < 688128) { src = s1; dh = h1; dl = l1; off = i - 602112; }
    else if (i < 725760) { src = s2; dh = h2; dl = l2; off = i - 688128; }
    else                 { src = s3; dh = h3; dl = l3; off = i - 725760; }
    const float4 v = ((const float4*)src)[off];
    union { __hip_bfloat16 b[4]; uint2 u; } H, L;
    split2(v.x, H.b[0], L.b[0]); split2(v.y, H.b[1], L.b[1]);
    split2(v.z, H.b[2], L.b[2]); split2(v.w, H.b[3], L.b[3]);
    ((uint2*)dh)[off] = H.u;
    ((uint2*)dl)[off] = L.u;
}

// ---------------------------------------------------------------------------
// Split-bf16 MFMA GEMM: C[M x N] = P[M x K] @ Q[N x K]^T (+bias), 3-pass hi/lo.
// 128x128 tile, 4 waves each 64x64 (4x4 frags of 16x16x32), BK=32.
// ---------------------------------------------------------------------------
template<int EPI>
__global__ __launch_bounds__(256) void k_mfma(
    const __hip_bfloat16* __restrict__ Phi, const __hip_bfloat16* __restrict__ Plo,
    const __hip_bfloat16* __restrict__ Qhi, const __hip_bfloat16* __restrict__ Qlo,
    const float* __restrict__ bias, int K, int nQ,
    float* __restrict__ out0, float* __restrict__ out1, float* __restrict__ out2)
{
    __shared__ ushort lds[16384];   // Ahi[0:4096) Alo[4096) Bhi[8192) Blo[12288) (ushort idx)
    const int t    = threadIdx.x;
    const int m0   = blockIdx.x * 128;
    const int n0   = blockIdx.y * 128;
    const int lane = t & 63;
    const int wv   = t >> 6;
    const int wm   = (wv >> 1) * 64;
    const int wn   = (wv & 1) * 64;
    const int l16  = lane & 15;
    const int kb   = lane >> 4;          // 0..3

    f32x4 acc[4][4];
    #pragma unroll
    for (int mi = 0; mi < 4; ++mi)
        #pragma unroll
        for (int nj = 0; nj < 4; ++nj) acc[mi][nj] = f32x4{0.f, 0.f, 0.f, 0.f};

    for (int k0 = 0; k0 < K; k0 += 32) {
        bf16x8 rA[2][2], rB[2][2];
        #pragma unroll
        for (int q = 0; q < 2; ++q) {
            const int u = q * 256 + t;
            const int r = u >> 2;
            const int kk = (u & 3) * 8;
            const size_t pOff = (size_t)(m0 + r) * K + k0 + kk;
            rA[q][0] = *(const bf16x8*)(Phi + pOff);
            rA[q][1] = *(const bf16x8*)(Plo + pOff);
            if (n0 + r < nQ) {
                const size_t qOff = (size_t)(n0 + r) * K + k0 + kk;
                rB[q][0] = *(const bf16x8*)(Qhi + qOff);
                rB[q][1] = *(const bf16x8*)(Qlo + qOff);
            } else { rB[q][0] = bf16x8_zero(); rB[q][1] = bf16x8_zero(); }
        }
        __syncthreads();   // prior iteration's LDS reads complete
        #pragma unroll
        for (int q = 0; q < 2; ++q) {
            const int u  = q * 256 + t;
            const int r  = u >> 2;
            const int sw = ((u << 4) ^ ((r & 7) << 4)) >> 1;   // ushort index
            *(bf16x8*)&lds[sw]         = rA[q][0];
            *(bf16x8*)&lds[sw + 4096]  = rA[q][1];
            *(bf16x8*)&lds[sw + 8192]  = rB[q][0];
            *(bf16x8*)&lds[sw + 12288] = rB[q][1];
        }
        __syncthreads();
        bf16x8 bh[4], bl[4];
        #pragma unroll
        for (int nj = 0; nj < 4; ++nj) {
            const int br  = wn + nj * 16 + l16;
            const int idx = ((br * 64 + kb * 16) ^ ((br & 7) << 4)) >> 1;
            bh[nj] = *(const bf16x8*)&lds[8192 + idx];
            bl[nj] = *(const bf16x8*)&lds[12288 + idx];
        }
        #pragma unroll
        for (int mi = 0; mi < 4; ++mi) {
            const int ar  = wm + mi * 16 + l16;
            const int idx = ((ar * 64 + kb * 16) ^ ((ar & 7) << 4)) >> 1;
            const bf16x8 ah = *(const bf16x8*)&lds[idx];
            const bf16x8 al = *(const bf16x8*)&lds[4096 + idx];
            #pragma unroll
            for (int nj = 0; nj < 4; ++nj) {
                acc[mi][nj] = __builtin_amdgcn_mfma_f32_16x16x32_bf16(ah, bh[nj], acc[mi][nj], 0, 0, 0);
                acc[mi][nj] = __builtin_amdgcn_mfma_f32_16x16x32_bf16(ah, bl[nj], acc[mi][nj], 0, 0, 0);
                acc[mi][nj] = __builtin_amdgcn_mfma_f32_16x16x32_bf16(al, bh[nj], acc[mi][nj], 0, 0, 0);
            }
        }
    }

    #pragma unroll
    for (int mi = 0; mi < 4; ++mi) {
        #pragma unroll
        for (int r = 0; r < 4; ++r) {
            const int m = m0 + wm + mi * 16 + kb * 4 + r;   // row = (lane>>4)*4 + reg
            #pragma unroll
            for (int nj = 0; nj < 4; ++nj) {
                const int col = n0 + wn + nj * 16 + l16;    // col = lane&15
                const float v = acc[mi][nj][r];
                if (EPI == 0) {
                    const float val = v + bias[col];
                    const int bb = m / N_, n = m - bb * N_;
                    if (col < DQK)          out0[((size_t)bb * DQK + col) * N_ + n] = val;
                    else if (col < 2*DQK)   out1[((size_t)bb * DQK + (col - DQK)) * N_ + n] = val;
                    else                    out2[((size_t)bb * DV + (col - 2*DQK)) * N_ + n] = val;
                } else if (EPI == 1) {
                    if (col < NPW) out0[(size_t)m * NPW + col] = v + bias[col];
                } else {
                    out0[(size_t)m * DV + col] = v + bias[col];
                }
            }
        }
    }
}

// ---------------------------------------------------------------------------
// K2: hp = q*k*SCALE ; grouped 7x7 conv ; +bias ; GELU -> split-bf16 h1t[b*n][256]
// ---------------------------------------------------------------------------
__global__ __launch_bounds__(256) void k_dwconv(const float* __restrict__ qT,
    const float* __restrict__ kT, const float* __restrict__ w_dw,
    const float* __restrict__ b_dw,
    __hip_bfloat16* __restrict__ h1t_hi, __hip_bfloat16* __restrict__ h1t_lo)
{
    const int b  = blockIdx.x;   // 32
    const int gp = blockIdx.y;   // 16 group-pairs
    __shared__ float hp[16 * 400];
    __shared__ float wsm[16 * 392];
    const int t = threadIdx.x;
    for (int i = t; i < 16 * 400; i += 256) hp[i] = 0.f;
    for (int i = t; i < 16 * 392; i += 256) wsm[i] = w_dw[gp * 6272 + i];
    __syncthreads();
    for (int i = t; i < 16 * N_; i += 256) {
        const int cl = i / N_;
        const int n  = i - cl * N_;
        const int y  = n / H_, x = n - y * H_;
        const size_t gi = ((size_t)b * DQK + gp * 16 + cl) * N_ + n;
        hp[cl * 400 + (y + PAD_) * 20 + (x + PAD_)] = qT[gi] * kT[gi] * SCALE_;
    }
    __syncthreads();
    if (t < 224) {
        const int od = t / 14;
        const int y  = t - od * 14;
        const int icb = (od >> 3) << 3;
        float acc[14];
        #pragma unroll
        for (int x = 0; x < 14; ++x) acc[x] = 0.f;
        for (int ic = 0; ic < 8; ++ic) {
            const float* hrow = &hp[(icb + ic) * 400];
            const float* wrow = &wsm[od * 392 + ic * 49];
            #pragma unroll
            for (int ky = 0; ky < 7; ++ky) {
                float r[20];
                #pragma unroll
                for (int ii = 0; ii < 20; ii += 4)
                    *(float4*)&r[ii] = *(const float4*)&hrow[(y + ky) * 20 + ii];
                #pragma unroll
                for (int kx = 0; kx < 7; ++kx) {
                    const float wv = wrow[ky * 7 + kx];
                    #pragma unroll
                    for (int x = 0; x < 14; ++x)
                        acc[x] += r[x + kx] * wv;
                }
            }
        }
        const float bv = b_dw[gp * 16 + od];
        const int c = gp * 16 + od;
        #pragma unroll
        for (int x = 0; x < 14; ++x) {
            const float s  = acc[x] + bv;
            const float gv = 0.5f * s * (1.f + erff(s * 0.70710678118654752440f));
            __hip_bfloat16 hb, lb; split2(gv, hb, lb);
            const size_t o = ((size_t)b * N_ + y * H_ + x) * DQK + c;
            h1t_hi[o] = hb; h1t_lo[o] = lb;
        }
    }
}

// ---------------------------------------------------------------------------
// K4 (restructured for occupancy): block=(b, g, chunk of 8 channels), 1536
// blocks, 16 KB LDS. Thread = spatial n; its 49 attn logits are 49 contiguous
// floats of h2t -> register softmax (no LDS attn staging). gm/ga interleaved
// in LDS, lane-uniform broadcast reads in the tap loop.
// ---------------------------------------------------------------------------
__global__ __launch_bounds__(256) void k_elsa(const float* __restrict__ h2t,
    const float* __restrict__ vT, const float* __restrict__ ghost,
    __hip_bfloat16* __restrict__ orm_hi, __hip_bfloat16* __restrict__ orm_lo)
{
    const int b  = blockIdx.x;   // 32
    const int g  = blockIdx.y;   // 12
    const int c0 = blockIdx.z * 8;  // channel chunk base
    __shared__ float vp[8 * 400];       // 12.8 KB, 8 ch x 20x20 padded
    __shared__ float gmga[8 * 49 * 2];  // 3.1 KB, [c][p][{mul,add}]
    const int t = threadIdx.x;

    // stage: zero pad + ghost coefs
    for (int i = t; i < 8 * 400; i += 256) vp[i] = 0.f;
    for (int i = t; i < 8 * 49; i += 256) {
        const int c = i / 49, p = i - c * 49;
        gmga[(c * 49 + p) * 2 + 0] = ghost[(size_t)(g * CG + c0 + c) * 49 + p];
        gmga[(c * 49 + p) * 2 + 1] = ghost[(size_t)DV * 49 + (g * CG + c0 + c) * 49 + p];
    }
    __syncthreads();
    // fill padded V interior
    for (int i = t; i < 8 * N_; i += 256) {
        const int c = i / N_;
        const int n = i - c * N_;
        const int y = n / H_, x = n - y * H_;
        vp[c * 400 + (y + PAD_) * 20 + (x + PAD_)] =
            vT[((size_t)b * DV + g * CG + c0 + c) * N_ + n];
    }
    __syncthreads();

    if (t < N_) {
        const int n = t;
        const int y = n / H_, x = n - y * H_;
        const int base = y * 20 + x;            // pad-corner window base
        const size_t m = (size_t)b * N_ + n;

        // register softmax over the 49 contiguous logits of this (b,n,g)
        const float* hr = h2t + m * NPW + g * 49;
        float a[49];
        #pragma unroll
        for (int p = 0; p < 49; ++p) a[p] = hr[p];
        float mx = -1e30f;
        #pragma unroll
        for (int p = 0; p < 49; ++p) mx = fmaxf(mx, a[p]);
        float ssum = 0.f;
        #pragma unroll
        for (int p = 0; p < 49; ++p) { a[p] = expf(a[p] - mx); ssum += a[p]; }
        const float inv = 1.f / ssum;
        #pragma unroll
        for (int p = 0; p < 49; ++p) a[p] *= inv;

        // 49-tap windowed sum for 8 channels (gm/ga lane-uniform broadcasts)
        #pragma unroll 1
        for (int c = 0; c < 8; ++c) {
            const float* vrow = &vp[c * 400 + base];
            const float* gg   = &gmga[c * 98];
            float s = 0.f;
            #pragma unroll
            for (int ky = 0; ky < 7; ++ky)
                #pragma unroll
                for (int kx = 0; kx < 7; ++kx) {
                    const int p = ky * 7 + kx;
                    s += vrow[ky * 20 + kx] * (gg[p * 2] * a[p] + gg[p * 2 + 1]);
                }
            __hip_bfloat16 hb, lb; split2(s, hb, lb);
            const size_t o = m * DV + g * CG + c0 + c;
            orm_hi[o] = hb; orm_lo[o] = lb;
        }
    }
}

// ---------------------------------------------------------------------------
extern "C" void kernel_launch(void* const* d_in, const int* in_sizes, int n_in,
                              void* d_out, int out_size, void* d_ws, size_t ws_size,
                              hipStream_t stream)
{
    const float* x      = (const float*)d_in[0];
    const float* w_qkv  = (const float*)d_in[1];
    const float* b_qkv  = (const float*)d_in[2];
    const float* w_dw   = (const float*)d_in[3];
    const float* b_dw   = (const float*)d_in[4];
    const float* w_pw   = (const float*)d_in[5];
    const float* b_pw   = (const float*)d_in[6];
    const float* ghost  = (const float*)d_in[7];
    const float* w_proj = (const float*)d_in[8];
    const float* b_proj = (const float*)d_in[9];
    float* y  = (float*)d_out;
    char* ws = (char*)d_ws;

    // Aliasing plan (stream-ordered lifetimes), peak 44.8 MB:
    //   [0,14751744):      x_hi/x_lo/wqkv_hi/wqkv_lo (live through qkv)
    //                      then h2t (written by pw, read by elsa)
    //   [14751744,27596800): qT,kT (live through dwconv)
    //                      then orm_hi/orm_lo (written by elsa, read by proj)
    //   [27596800,37230592): vT (live through elsa)
    //   [37230592,44845056): wpw/wproj splits + h1t splits
    __hip_bfloat16* x_hi     = (__hip_bfloat16*)(ws + 0);
    __hip_bfloat16* x_lo     = (__hip_bfloat16*)(ws + 4816896);
    __hip_bfloat16* wqkv_hi  = (__hip_bfloat16*)(ws + 9633792);
    __hip_bfloat16* wqkv_lo  = (__hip_bfloat16*)(ws + 10321920);
    float*          h2t      = (float*)         (ws + 0);            // alias, 14751744 B
    float*          qT       = (float*)         (ws + 14751744);
    float*          kT       = (float*)         (ws + 21174272);
    __hip_bfloat16* orm_hi   = (__hip_bfloat16*)(ws + 14751744);     // alias qT/kT region
    __hip_bfloat16* orm_lo   = (__hip_bfloat16*)(ws + 19568640);
    float*          vT       = (float*)         (ws + 27596800);
    __hip_bfloat16* wpw_hi   = (__hip_bfloat16*)(ws + 37230592);
    __hip_bfloat16* wpw_lo   = (__hip_bfloat16*)(ws + 37531648);
    __hip_bfloat16* wproj_hi = (__hip_bfloat16*)(ws + 37832704);
    __hip_bfloat16* wproj_lo = (__hip_bfloat16*)(ws + 38127616);
    __hip_bfloat16* h1t_hi   = (__hip_bfloat16*)(ws + 38422528);
    __hip_bfloat16* h1t_lo   = (__hip_bfloat16*)(ws + 41633792);

    k_split<<<2979, 256, 0, stream>>>(x, w_qkv, w_pw, w_proj,
        x_hi, x_lo, wqkv_hi, wqkv_lo, wpw_hi, wpw_lo, wproj_hi, wproj_lo);

    k_mfma<0><<<dim3(49, 7), 256, 0, stream>>>(x_hi, x_lo, wqkv_hi, wqkv_lo,
        b_qkv, DIMC, 896, qT, kT, vT);

    k_dwconv<<<dim3(32, 16), 256, 0, stream>>>(qT, kT, w_dw, b_dw, h1t_hi, h1t_lo);

    k_mfma<1><<<dim3(49, 5), 256, 0, stream>>>(h1t_hi, h1t_lo, wpw_hi, wpw_lo,
        b_pw, DQK, NPW, h2t, nullptr, nullptr);

    k_elsa<<<dim3(32, 12, 4), 256, 0, stream>>>(h2t, vT, ghost, orm_hi, orm_lo);

    k_mfma<2><<<dim3(49, 3), 256, 0, stream>>>(orm_hi, orm_lo, wproj_hi, wproj_lo,
        b_proj, DV, DV, y, nullptr, nullptr);
}

// Round 11
// 216.555 us; speedup vs baseline: 1.4985x; 1.1169x over previous
//
#include <hip/hip_runtime.h>
#include <hip/hip_bf16.h>

#define B_    32
#define N_    196
#define H_    14
#define DIMC  384
#define DQK   256
#define DV    384
#define NH    12
#define CG    32
#define NPW   588
#define PAD_  3
#define SCALE_ 0.17677669529663687f   // (384/12)^-0.5

typedef __bf16 bf16x8 __attribute__((ext_vector_type(8)));
typedef float  f32x4  __attribute__((ext_vector_type(4)));

__device__ inline bf16x8 bf16x8_zero() {
    bf16x8 z;
    #pragma unroll
    for (int j = 0; j < 8; ++j) z[j] = (__bf16)0.0f;
    return z;
}

// ---------------------------------------------------------------------------
// K0: round fp32 -> bf16 for x, w_qkv, w_pw, w_proj. float4 per thread.
// segment float4 boundaries: x 602112 | wqkv 86016 | wpw 37632 | wproj 36864
// ---------------------------------------------------------------------------
__global__ __launch_bounds__(256) void k_split(
    const float* __restrict__ s0, const float* __restrict__ s1,
    const float* __restrict__ s2, const float* __restrict__ s3,
    __hip_bfloat16* __restrict__ d0, __hip_bfloat16* __restrict__ d1,
    __hip_bfloat16* __restrict__ d2, __hip_bfloat16* __restrict__ d3)
{
    int i = blockIdx.x * 256 + threadIdx.x;
    if (i >= 762624) return;
    const float* src; __hip_bfloat16* dst; int off;
    if      (i < 602112) { src = s0; dst = d0; off = i; }
    else if (i < 688128) { src = s1; dst = d1; off = i - 602112; }
    else if (i < 725760) { src = s2; dst = d2; off = i - 688128; }
    else                 { src = s3; dst = d3; off = i - 725760; }
    const float4 v = ((const float4*)src)[off];
    union { __hip_bfloat16 b[4]; uint2 u; } Hh;
    Hh.b[0] = __float2bfloat16(v.x); Hh.b[1] = __float2bfloat16(v.y);
    Hh.b[2] = __float2bfloat16(v.z); Hh.b[3] = __float2bfloat16(v.w);
    ((uint2*)dst)[off] = Hh.u;
}

// ---------------------------------------------------------------------------
// bf16 MFMA GEMM (single-pass, fp32 accum): C[M x N] = P @ Q^T (+bias).
// 128x128 tile, 4 waves each 64x64 (4x4 frags of 16x16x32), BK=32.
// LDS XOR swizzle byte ^= (row&7)<<4, identical map on write+read.
// EPI 0: qkv scatter to channel-major qT/kT/vT (fp32).
// EPI 1: h2 channel-major [b][oc][196] (fp32, guard col<588).
// EPI 2: y row-major (fp32).
// ---------------------------------------------------------------------------
template<int EPI>
__global__ __launch_bounds__(256) void k_mfma(
    const __hip_bfloat16* __restrict__ P, const __hip_bfloat16* __restrict__ Q,
    const float* __restrict__ bias, int K, int nQ,
    float* __restrict__ out0, float* __restrict__ out1, float* __restrict__ out2)
{
    __shared__ ushort lds[8192];   // A[0:4096) B[4096:8192) (ushort idx)
    const int t    = threadIdx.x;
    const int m0   = blockIdx.x * 128;
    const int n0   = blockIdx.y * 128;
    const int lane = t & 63;
    const int wv   = t >> 6;
    const int wm   = (wv >> 1) * 64;
    const int wn   = (wv & 1) * 64;
    const int l16  = lane & 15;
    const int kb   = lane >> 4;          // 0..3

    f32x4 acc[4][4];
    #pragma unroll
    for (int mi = 0; mi < 4; ++mi)
        #pragma unroll
        for (int nj = 0; nj < 4; ++nj) acc[mi][nj] = f32x4{0.f, 0.f, 0.f, 0.f};

    for (int k0 = 0; k0 < K; k0 += 32) {
        bf16x8 rA[2], rB[2];
        #pragma unroll
        for (int q = 0; q < 2; ++q) {
            const int u = q * 256 + t;
            const int r = u >> 2;
            const int kk = (u & 3) * 8;
            rA[q] = *(const bf16x8*)(P + (size_t)(m0 + r) * K + k0 + kk);
            rB[q] = (n0 + r < nQ)
                  ? *(const bf16x8*)(Q + (size_t)(n0 + r) * K + k0 + kk)
                  : bf16x8_zero();
        }
        __syncthreads();   // prior iteration's LDS reads complete
        #pragma unroll
        for (int q = 0; q < 2; ++q) {
            const int u  = q * 256 + t;
            const int r  = u >> 2;
            const int sw = ((u << 4) ^ ((r & 7) << 4)) >> 1;   // ushort index
            *(bf16x8*)&lds[sw]        = rA[q];
            *(bf16x8*)&lds[sw + 4096] = rB[q];
        }
        __syncthreads();
        bf16x8 bh[4];
        #pragma unroll
        for (int nj = 0; nj < 4; ++nj) {
            const int br  = wn + nj * 16 + l16;
            const int idx = ((br * 64 + kb * 16) ^ ((br & 7) << 4)) >> 1;
            bh[nj] = *(const bf16x8*)&lds[4096 + idx];
        }
        #pragma unroll
        for (int mi = 0; mi < 4; ++mi) {
            const int ar  = wm + mi * 16 + l16;
            const int idx = ((ar * 64 + kb * 16) ^ ((ar & 7) << 4)) >> 1;
            const bf16x8 ah = *(const bf16x8*)&lds[idx];
            #pragma unroll
            for (int nj = 0; nj < 4; ++nj)
                acc[mi][nj] = __builtin_amdgcn_mfma_f32_16x16x32_bf16(ah, bh[nj], acc[mi][nj], 0, 0, 0);
        }
    }

    #pragma unroll
    for (int mi = 0; mi < 4; ++mi) {
        #pragma unroll
        for (int r = 0; r < 4; ++r) {
            const int m = m0 + wm + mi * 16 + kb * 4 + r;   // row = (lane>>4)*4 + reg
            #pragma unroll
            for (int nj = 0; nj < 4; ++nj) {
                const int col = n0 + wn + nj * 16 + l16;    // col = lane&15
                const float v = acc[mi][nj][r];
                if (EPI == 0) {
                    const float val = v + bias[col];
                    const int bb = m / N_, n = m - bb * N_;
                    if (col < DQK)          out0[((size_t)bb * DQK + col) * N_ + n] = val;
                    else if (col < 2*DQK)   out1[((size_t)bb * DQK + (col - DQK)) * N_ + n] = val;
                    else                    out2[((size_t)bb * DV + (col - 2*DQK)) * N_ + n] = val;
                } else if (EPI == 1) {
                    if (col < NPW) {
                        const int bb = m / N_, n = m - bb * N_;
                        out0[((size_t)bb * NPW + col) * N_ + n] = v + bias[col];
                    }
                } else {
                    out0[(size_t)m * DV + col] = v + bias[col];
                }
            }
        }
    }
}

// ---------------------------------------------------------------------------
// K2: hp = q*k*SCALE ; grouped 7x7 conv ; +bias ; GELU -> bf16 h1t[b*n][256]
// ---------------------------------------------------------------------------
__global__ __launch_bounds__(256) void k_dwconv(const float* __restrict__ qT,
    const float* __restrict__ kT, const float* __restrict__ w_dw,
    const float* __restrict__ b_dw, __hip_bfloat16* __restrict__ h1t)
{
    const int b  = blockIdx.x;   // 32
    const int gp = blockIdx.y;   // 16 group-pairs
    __shared__ float hp[16 * 400];
    __shared__ float wsm[16 * 392];
    const int t = threadIdx.x;
    for (int i = t; i < 16 * 400; i += 256) hp[i] = 0.f;
    for (int i = t; i < 16 * 392; i += 256) wsm[i] = w_dw[gp * 6272 + i];
    __syncthreads();
    for (int i = t; i < 16 * N_; i += 256) {
        const int cl = i / N_;
        const int n  = i - cl * N_;
        const int y  = n / H_, x = n - y * H_;
        const size_t gi = ((size_t)b * DQK + gp * 16 + cl) * N_ + n;
        hp[cl * 400 + (y + PAD_) * 20 + (x + PAD_)] = qT[gi] * kT[gi] * SCALE_;
    }
    __syncthreads();
    if (t < 224) {
        const int od = t / 14;
        const int y  = t - od * 14;
        const int icb = (od >> 3) << 3;
        float acc[14];
        #pragma unroll
        for (int x = 0; x < 14; ++x) acc[x] = 0.f;
        for (int ic = 0; ic < 8; ++ic) {
            const float* hrow = &hp[(icb + ic) * 400];
            const float* wrow = &wsm[od * 392 + ic * 49];
            #pragma unroll
            for (int ky = 0; ky < 7; ++ky) {
                float r[20];
                #pragma unroll
                for (int ii = 0; ii < 20; ii += 4)
                    *(float4*)&r[ii] = *(const float4*)&hrow[(y + ky) * 20 + ii];
                #pragma unroll
                for (int kx = 0; kx < 7; ++kx) {
                    const float wv = wrow[ky * 7 + kx];
                    #pragma unroll
                    for (int x = 0; x < 14; ++x)
                        acc[x] += r[x + kx] * wv;
                }
            }
        }
        const float bv = b_dw[gp * 16 + od];
        const int c = gp * 16 + od;
        #pragma unroll
        for (int x = 0; x < 14; ++x) {
            const float s  = acc[x] + bv;
            const float gv = 0.5f * s * (1.f + erff(s * 0.70710678118654752440f));
            h1t[((size_t)b * N_ + y * H_ + x) * DQK + c] = __float2bfloat16(gv);
        }
    }
}

// ---------------------------------------------------------------------------
// K4: block=(b, g, chunk of 8 channels), 1536 blocks, 16 KB LDS.
// h2c is channel-major [b][oc][196]: thread n reads its 49 logits at
// lane-contiguous addresses (coalesced). Register softmax, 49-tap sum.
// ---------------------------------------------------------------------------
__global__ __launch_bounds__(256) void k_elsa(const float* __restrict__ h2c,
    const float* __restrict__ vT, const float* __restrict__ ghost,
    __hip_bfloat16* __restrict__ orm)
{
    const int b  = blockIdx.x;   // 32
    const int g  = blockIdx.y;   // 12
    const int c0 = blockIdx.z * 8;  // channel chunk base
    __shared__ float vp[8 * 400];       // 12.8 KB, 8 ch x 20x20 padded
    __shared__ float gmga[8 * 49 * 2];  // 3.1 KB, [c][p][{mul,add}]
    const int t = threadIdx.x;

    for (int i = t; i < 8 * 400; i += 256) vp[i] = 0.f;
    for (int i = t; i < 8 * 49; i += 256) {
        const int c = i / 49, p = i - c * 49;
        gmga[(c * 49 + p) * 2 + 0] = ghost[(size_t)(g * CG + c0 + c) * 49 + p];
        gmga[(c * 49 + p) * 2 + 1] = ghost[(size_t)DV * 49 + (g * CG + c0 + c) * 49 + p];
    }
    __syncthreads();
    for (int i = t; i < 8 * N_; i += 256) {
        const int c = i / N_;
        const int n = i - c * N_;
        const int y = n / H_, x = n - y * H_;
        vp[c * 400 + (y + PAD_) * 20 + (x + PAD_)] =
            vT[((size_t)b * DV + g * CG + c0 + c) * N_ + n];
    }
    __syncthreads();

    if (t < N_) {
        const int n = t;
        const int y = n / H_, x = n - y * H_;
        const int base = y * 20 + x;            // pad-corner window base

        // coalesced register softmax: logits at stride N_ across p
        const float* hr = h2c + ((size_t)b * NPW + g * 49) * N_ + n;
        float a[49];
        #pragma unroll
        for (int p = 0; p < 49; ++p) a[p] = hr[(size_t)p * N_];
        float mx = -1e30f;
        #pragma unroll
        for (int p = 0; p < 49; ++p) mx = fmaxf(mx, a[p]);
        float ssum = 0.f;
        #pragma unroll
        for (int p = 0; p < 49; ++p) { a[p] = expf(a[p] - mx); ssum += a[p]; }
        const float inv = 1.f / ssum;
        #pragma unroll
        for (int p = 0; p < 49; ++p) a[p] *= inv;

        const size_t m = (size_t)b * N_ + n;
        #pragma unroll 1
        for (int c = 0; c < 8; ++c) {
            const float* vrow = &vp[c * 400 + base];
            const float* gg   = &gmga[c * 98];
            float s = 0.f;
            #pragma unroll
            for (int ky = 0; ky < 7; ++ky)
                #pragma unroll
                for (int kx = 0; kx < 7; ++kx) {
                    const int p = ky * 7 + kx;
                    s += vrow[ky * 20 + kx] * (gg[p * 2] * a[p] + gg[p * 2 + 1]);
                }
            orm[m * DV + g * CG + c0 + c] = __float2bfloat16(s);
        }
    }
}

// ---------------------------------------------------------------------------
extern "C" void kernel_launch(void* const* d_in, const int* in_sizes, int n_in,
                              void* d_out, int out_size, void* d_ws, size_t ws_size,
                              hipStream_t stream)
{
    const float* x      = (const float*)d_in[0];
    const float* w_qkv  = (const float*)d_in[1];
    const float* b_qkv  = (const float*)d_in[2];
    const float* w_dw   = (const float*)d_in[3];
    const float* b_dw   = (const float*)d_in[4];
    const float* w_pw   = (const float*)d_in[5];
    const float* b_pw   = (const float*)d_in[6];
    const float* ghost  = (const float*)d_in[7];
    const float* w_proj = (const float*)d_in[8];
    const float* b_proj = (const float*)d_in[9];
    float* y  = (float*)d_out;
    char* ws = (char*)d_ws;

    // Aliasing plan (stream-ordered lifetimes), peak ~41 MB:
    //   [0,14751744):        x_bf+wqkv_bf (live through qkv) then h2c (pw->elsa)
    //   [14751744,27596800): qT,kT (live through dwconv) then orm_bf (elsa->proj)
    //   [27596800,37230592): vT (live through elsa)
    //   [37230592,41037824): wpw_bf, wproj_bf, h1t_bf
    __hip_bfloat16* x_bf     = (__hip_bfloat16*)(ws + 0);
    __hip_bfloat16* wqkv_bf  = (__hip_bfloat16*)(ws + 4816896);
    float*          h2c      = (float*)         (ws + 0);            // alias
    float*          qT       = (float*)         (ws + 14751744);
    float*          kT       = (float*)         (ws + 21174272);
    __hip_bfloat16* orm_bf   = (__hip_bfloat16*)(ws + 14751744);     // alias qT/kT
    float*          vT       = (float*)         (ws + 27596800);
    __hip_bfloat16* wpw_bf   = (__hip_bfloat16*)(ws + 37230592);
    __hip_bfloat16* wproj_bf = (__hip_bfloat16*)(ws + 37531648);
    __hip_bfloat16* h1t_bf   = (__hip_bfloat16*)(ws + 37826560);

    k_split<<<2979, 256, 0, stream>>>(x, w_qkv, w_pw, w_proj,
        x_bf, wqkv_bf, wpw_bf, wproj_bf);

    k_mfma<0><<<dim3(49, 7), 256, 0, stream>>>(x_bf, wqkv_bf,
        b_qkv, DIMC, 896, qT, kT, vT);

    k_dwconv<<<dim3(32, 16), 256, 0, stream>>>(qT, kT, w_dw, b_dw, h1t_bf);

    k_mfma<1><<<dim3(49, 5), 256, 0, stream>>>(h1t_bf, wpw_bf,
        b_pw, DQK, NPW, h2c, nullptr, nullptr);

    k_elsa<<<dim3(32, 12, 4), 256, 0, stream>>>(h2c, vT, ghost, orm_bf);

    k_mfma<2><<<dim3(49, 3), 256, 0, stream>>>(orm_bf, wproj_bf,
        b_proj, DV, DV, y, nullptr, nullptr);
}